// Round 11
// baseline (278.874 us; speedup 1.0000x reference)
//
#include <hip/hip_runtime.h>
#include <stdint.h>

typedef unsigned short u16;
typedef __attribute__((ext_vector_type(8))) short bf16x8;
typedef __attribute__((ext_vector_type(8))) unsigned short u16x8;
typedef __attribute__((ext_vector_type(4))) float f32x4;
typedef __attribute__((ext_vector_type(16))) float f32x16;

#define S_LEN 2048
#define EDIM 1024
#define NH 16
#define HD 64

static __device__ __forceinline__ u16 f2bf(float f) {
  union { float f; uint32_t u; } v; v.f = f;
  uint32_t r = v.u + 0x7fffu + ((v.u >> 16) & 1u);  // RNE
  return (u16)(r >> 16);
}

// packed f32x2 -> bf16x2 (RNE), low=a high=b (validated v8-v12)
static __device__ __forceinline__ uint32_t cvtpk_bf16(float a, float b) {
  uint32_t r;
  asm("v_cvt_pk_bf16_f32 %0, %1, %2" : "=v"(r) : "v"(a), "v"(b));
  return r;
}

// async global->LDS, 16B per lane; LDS dest = wave-uniform base + lane*16
static __device__ __forceinline__ void gload_lds16(const u16* g, u16* l) {
  __builtin_amdgcn_global_load_lds(
      (const __attribute__((address_space(1))) void*)g,
      (__attribute__((address_space(3))) void*)l, 16, 0, 0);
}

// pinned 16B global load (used for Q prologue only)
static __device__ __forceinline__ bf16x8 gload16(const u16* p) {
  bf16x8 r;
  asm volatile("global_load_dwordx4 %0, %1, off" : "=v"(r) : "v"(p));
  return r;
}

// counted wait + full scheduling fence (rule #18)
#define WAIT_VM(n)                                   \
  do {                                               \
    asm volatile("s_waitcnt vmcnt(" #n ")");         \
    __builtin_amdgcn_sched_barrier(0);               \
  } while (0)

#define BARRIER()                                    \
  do {                                               \
    __builtin_amdgcn_s_barrier();                    \
    __builtin_amdgcn_sched_barrier(0);               \
  } while (0)

// ---------------------------------------------------------------------------
// pack v3: x fp32->bf16 vectorized; W transposes via LDS 64x64 tiles.
// Wq pre-scaled by D^-0.5*log2(e): scores come out of QKV GEMM exp2-ready.
// Blocks: [0,8192) x-convert; [8192,8960) wqkv; [8960,9216) wproj.
// ---------------------------------------------------------------------------
__global__ __launch_bounds__(256) void pack_inputs(
    const float* __restrict__ x, const float* __restrict__ Wq,
    const float* __restrict__ Wk, const float* __restrict__ Wv,
    const float* __restrict__ Wp,
    u16* __restrict__ xb, u16* __restrict__ wqkvT, u16* __restrict__ wprojT) {
  const int blk = blockIdx.x;
  const int tid = threadIdx.x;
  if (blk < 8192) {
    int idx = blk * 256 + tid;  // 2,097,152 float4 groups total
    float4 v = ((const float4*)x)[idx];
    ushort4 o;
    o.x = f2bf(v.x); o.y = f2bf(v.y); o.z = f2bf(v.z); o.w = f2bf(v.w);
    ((ushort4*)xb)[idx] = o;
    return;
  }
  __shared__ u16 tile[64][65];  // +1 pad: gather phase 2-way banked (free)
  const float* src;
  size_t src_rs;   // src row stride (floats)
  u16* dst;        // dst tile base: dst + r*1024 + c
  float wscale = 1.0f;
  if (blk < 8960) {
    int t = blk - 8192;          // 0..767
    int mh = t >> 4;             // 0..47
    int et = t & 15;             // e-tile
    int m = mh >> 4, h = mh & 15;
    const float* W = (m == 0) ? Wq : (m == 1) ? Wk : Wv;
    if (m == 0) wscale = 0.1803368801111204f;  // D^-0.5 * log2(e)
    src = W + ((size_t)(h * EDIM + et * 64)) * HD;
    src_rs = HD;
    dst = wqkvT + (size_t)(m * 1024 + h * 64) * 1024 + et * 64;
  } else {
    int t = blk - 8960;          // 0..255
    int kt = t >> 4, nt = t & 15;
    src = Wp + (size_t)(kt * 64) * 1024 + nt * 64;
    src_rs = 1024;
    dst = wprojT + (size_t)(nt * 64) * 1024 + kt * 64;
  }
  {
    const int rr = tid >> 4;        // 0..15
    const int c4 = (tid & 15) << 2; // 0..60
#pragma unroll
    for (int p = 0; p < 4; p++) {
      const int r = p * 16 + rr;
      float4 v = *(const float4*)(src + (size_t)r * src_rs + c4);
      tile[r][c4 + 0] = f2bf(v.x * wscale);
      tile[r][c4 + 1] = f2bf(v.y * wscale);
      tile[r][c4 + 2] = f2bf(v.z * wscale);
      tile[r][c4 + 3] = f2bf(v.w * wscale);
    }
  }
  __syncthreads();
  {
    const int rr = tid >> 3;        // 0..31
    const int c8 = (tid & 7) << 3;  // 0..56
#pragma unroll
    for (int p = 0; p < 2; p++) {
      const int r = p * 32 + rr;    // out row (= src col)
      u16x8 o;
#pragma unroll
      for (int j = 0; j < 8; j++) o[j] = tile[c8 + j][r];
      *(u16x8*)(dst + (size_t)r * 1024 + c8) = o;
    }
  }
}

// ---------------------------------------------------------------------------
// 128x128-tile bf16 MFMA GEMM, BK=64:  C[M,N] = A[M,K] @ Bt[N,K]^T.
// (unchanged from round 5 — BK=64 + slot-XOR swizzle)
// ---------------------------------------------------------------------------
template <int EPI>
__global__ __launch_bounds__(256) void gemm128(
    const u16* __restrict__ A, const u16* __restrict__ Bt,
    const float* __restrict__ bias,
    u16* __restrict__ o0, u16* __restrict__ o1, u16* __restrict__ o2,
    float* __restrict__ of, int K, int N) {
  __shared__ __align__(16) u16 As[128 * 64];  // 16 KB, linear dest (lds-dma)
  __shared__ __align__(16) u16 Bs[128 * 64];
  const int tid  = threadIdx.x;
  const int lane = tid & 63;
  const int wave = tid >> 6;
  const int wm = wave >> 1;
  const int wn = wave & 1;
  const int col = lane & 15;
  const int quad = lane >> 4;
  const int cs = col & 7;
  const int m0 = blockIdx.y << 7;
  const int n0 = blockIdx.x << 7;

  const int srow  = lane >> 3;
  const int sslot = (lane & 7) ^ srow;
  const u16* gA = A + (size_t)(m0 + (wave << 5) + srow) * K + sslot * 8;
  const u16* gB = Bt + (size_t)(n0 + (wave << 5) + srow) * K + sslot * 8;
  u16* lA = &As[(wave << 5) << 6];
  u16* lB = &Bs[(wave << 5) << 6];

  f32x4 acc[4][4];
#pragma unroll
  for (int i = 0; i < 4; i++)
#pragma unroll
    for (int j = 0; j < 4; j++) acc[i][j] = (f32x4){0.f, 0.f, 0.f, 0.f};

  for (int kk = 0; kk < K; kk += 64) {
    __syncthreads();
#pragma unroll
    for (int i = 0; i < 4; i++) {
      gload_lds16(gA + (size_t)(i * 8) * K + kk, lA + i * 512);
      gload_lds16(gB + (size_t)(i * 8) * K + kk, lB + i * 512);
    }
    __syncthreads();

#pragma unroll
    for (int x = 0; x < 2; x++) {  // k-halves: k = x*32 + quad*8
      bf16x8 af[4], bfr[4];
#pragma unroll
      for (int i = 0; i < 4; i++)
        af[i] = *(const bf16x8*)(
            &As[((wm * 64 + i * 16 + col) << 6) + ((((x << 2) + quad) ^ cs) << 3)]);
#pragma unroll
      for (int j = 0; j < 4; j++)
        bfr[j] = *(const bf16x8*)(
            &Bs[((wn * 64 + j * 16 + col) << 6) + ((((x << 2) + quad) ^ cs) << 3)]);
#pragma unroll
      for (int i = 0; i < 4; i++)
#pragma unroll
        for (int j = 0; j < 4; j++)
          acc[i][j] = __builtin_amdgcn_mfma_f32_16x16x32_bf16(af[i], bfr[j],
                                                              acc[i][j], 0, 0, 0);
    }
  }

#pragma unroll
  for (int i = 0; i < 4; i++) {
#pragma unroll
    for (int j = 0; j < 4; j++) {
      // C/D layout: col=lane&15, row=quad*4+reg  [m89-verified]
      const int rg0 = m0 + wm * 64 + i * 16 + quad * 4;
      const int cg = n0 + wn * 64 + j * 16 + col;
      if (EPI == 0) {
        const int mat = cg >> 10;
        const int rem = cg & 1023;
        const int h = rem >> 6;
        const int d = rem & 63;
        const int b = rg0 >> 11;
        const int s0 = rg0 & 2047;
        if (mat == 2) {
          ushort4 o;
          o.x = f2bf(acc[i][j][0]); o.y = f2bf(acc[i][j][1]);
          o.z = f2bf(acc[i][j][2]); o.w = f2bf(acc[i][j][3]);
          *(ushort4*)(&o2[(((size_t)(b * NH + h) * HD + d) << 11) + s0]) = o;
        } else {
          u16* dst = (mat == 0) ? o0 : o1;
#pragma unroll
          for (int r = 0; r < 4; r++)
            dst[((size_t)((b * NH + h) * S_LEN + s0 + r) << 6) + d] =
                f2bf(acc[i][j][r]);
        }
      } else {
#pragma unroll
        for (int r = 0; r < 4; r++)
          of[(size_t)(rg0 + r) * N + cg] = acc[i][j][r] + bias[cg];
      }
    }
  }
}

// ---------------------------------------------------------------------------
// Fused causal flash attention v13 — v12 compute body, KVBLK=128/barrier.
// Ablation chain: v7/v10/v11/v12 (VALU count, P-LDS, MFMA count, pipeline
// depth all varied) = 79us -> per-iteration FIXED overhead ~4.4k cyc is the
// wall. v13 amortizes it: heavy block 32 -> 16 iterations; one STAGE(8 ld) +
// one vmcnt(0)+barrier per 128 kv. Compute body kept verbatim (lambda called
// twice per iteration on kv-halves); K/V LDS = [dbuf][half] pairs of the
// identical swizzled 64x64 tiles. LDS 64KB -> 2 blocks/CU (accepted:
// makespan is heavy-block-latency-bound, not residency-bound).
// Diagnostic read: dur ~55 => fixed-overhead confirmed (next: KVBLK=256);
// dur ~79 => overhead scales with bytes => DMA-throughput, halve traffic.
// ---------------------------------------------------------------------------
__global__ __launch_bounds__(256, 3) void attn_fused(
    const u16* __restrict__ Q, const u16* __restrict__ K,
    const u16* __restrict__ Vt, u16* __restrict__ O) {
  __shared__ __align__(16) u16 Kbuf[2][2][64 * 64];  // [dbuf][half][kv][d]
  __shared__ __align__(16) u16 Vbuf[2][2][64 * 64];  // [dbuf][half][d][kv]

  const int tid  = threadIdx.x;
  const int lane = tid & 63;
  const int wave = tid >> 6;
  const int q31  = lane & 31;
  const int hi   = lane >> 5;
  const int gid  = blockIdx.x;
  const int bh = ((gid & 7) << 3) | ((gid >> 3) & 7);  // 8 bh per XCD
  const int qb = 15 - (gid >> 6);                      // heavy-first
  const int b = bh >> 4;
  const int h = bh & 15;
  const int q0w = qb * 128 + wave * 32;                // wave's q base

  const u16* Kbh = K + (size_t)bh * S_LEN * HD;
  const u16* Vbh = Vt + (size_t)bh * HD * S_LEN;

  // staging lane constants: instr covers 8 rows
  const int srow  = lane >> 3;                  // 0..7
  const int sslot = (lane & 7) ^ srow;          // 0..7 (inverse swizzle)
  const int r0a = wave * 16;
  const int r0b = wave * 16 + 8;

  const int qs = q31 & 7;  // row&7 for frag-read swizzle

  // Q fragments: B-operand of mfma(K,Q): q=lane&31, chunk slot = m*2+hi
  bf16x8 qf[4];
  {
    const u16* Qrow = Q + ((size_t)bh * S_LEN + q0w + q31) * HD;
#pragma unroll
    for (int m = 0; m < 4; m++) qf[m] = gload16(Qrow + (((m << 1) + hi) << 3));
  }

  f32x16 oacc[2];  // O^T: oacc[db][r] = O[q][d=db*32+(r&3)+8*(r>>2)+4*hi]
#pragma unroll
  for (int db = 0; db < 2; db++)
#pragma unroll
    for (int r = 0; r < 16; r++) oacc[db][r] = 0.f;
  float lacc = 0.f;  // partial row-sum (own half's k-values)

  // stage one 64-kv sub-tile (4 loads/wave) into (kb, vb)
  auto STAGE64 = [&](u16* kb, u16* vb, int kv0) {
    gload_lds16(Kbh + (size_t)(kv0 + r0a + srow) * HD + sslot * 8, kb + r0a * 64);
    gload_lds16(Kbh + (size_t)(kv0 + r0b + srow) * HD + sslot * 8, kb + r0b * 64);
    gload_lds16(Vbh + (size_t)(r0a + srow) * S_LEN + kv0 + sslot * 8, vb + r0a * 64);
    gload_lds16(Vbh + (size_t)(r0b + srow) * S_LEN + kv0 + sslot * 8, vb + r0b * 64);
  };

  // v12 compute body, verbatim, on one 64-kv sub-tile
  auto BODY = [&](const u16* kb, const u16* vb, int kv0) {
    // --- swapped QK^T: sct[cb] = S^T over kv rows [cb*32, cb*32+32) ----
    f32x16 sct[2];
#pragma unroll
    for (int cb = 0; cb < 2; cb++) {
#pragma unroll
      for (int r = 0; r < 16; r++) sct[cb][r] = 0.f;
      const u16* kr = kb + ((cb << 5) + q31) * 64;
#pragma unroll
      for (int m = 0; m < 4; m++) {
        const bf16x8 kf = *(const bf16x8*)(kr + ((((m << 1) + hi) ^ qs) << 3));
        sct[cb] = __builtin_amdgcn_mfma_f32_32x32x16_bf16(kf, qf[m], sct[cb], 0, 0, 0);
      }
    }

    // --- softmax in-register: p = exp2(s) (pre-scaled), pack bf16 ------
    uint32_t pk[2][8];
    const bool diag = (kv0 + 63 > q0w);
    const int qg = q0w + q31;
#pragma unroll
    for (int cb = 0; cb < 2; cb++) {
#pragma unroll
      for (int u = 0; u < 8; u++) {
        float p0 = exp2f(sct[cb][2 * u]);
        float p1 = exp2f(sct[cb][2 * u + 1]);
        if (diag) {
          const int k0 = kv0 + (cb << 5) + ((2 * u) & 3) + 8 * (u >> 1) + 4 * hi;
          if (k0 > qg) p0 = 0.f;
          if (k0 + 1 > qg) p1 = 0.f;
        }
        lacc += p0 + p1;
        pk[cb][u] = cvtpk_bf16(p0, p1);
      }
    }

    // --- PV: B-frag per 16-k block via halves exchange, mfma(V^T,P^T) --
#pragma unroll
    for (int m = 0; m < 4; m++) {
      const int cb = m >> 1;
      const int bb = (m & 1) << 2;  // u base: 0 or 4
      const uint32_t x0 = (uint32_t)__shfl_xor((int)pk[cb][bb + 0], 32);
      const uint32_t x1 = (uint32_t)__shfl_xor((int)pk[cb][bb + 1], 32);
      const uint32_t x2 = (uint32_t)__shfl_xor((int)pk[cb][bb + 2], 32);
      const uint32_t x3 = (uint32_t)__shfl_xor((int)pk[cb][bb + 3], 32);
      union { uint32_t u[4]; bf16x8 v; } P;
      P.u[0] = hi ? x2 : pk[cb][bb + 0];
      P.u[1] = hi ? x3 : pk[cb][bb + 1];
      P.u[2] = hi ? pk[cb][bb + 2] : x0;
      P.u[3] = hi ? pk[cb][bb + 3] : x1;
#pragma unroll
      for (int db = 0; db < 2; db++) {
        const bf16x8 vf = *(const bf16x8*)(
            vb + ((db << 5) + q31) * 64 + ((((m << 1) + hi) ^ qs) << 3));
        oacc[db] = __builtin_amdgcn_mfma_f32_32x32x16_bf16(vf, P.v, oacc[db], 0, 0, 0);
      }
    }
  };

  const int T = qb + 1;  // 128-kv tiles: 0..T-1
  STAGE64(Kbuf[0][0], Vbuf[0][0], 0);
  STAGE64(Kbuf[0][1], Vbuf[0][1], 64);
  WAIT_VM(0);  // Q + tile 0 resident
  BARRIER();

  int cur = 0;
  for (int t = 0; t < T; t++) {
    const int kv0 = t << 7;
    if (t + 1 < T) {
      STAGE64(Kbuf[cur ^ 1][0], Vbuf[cur ^ 1][0], kv0 + 128);
      STAGE64(Kbuf[cur ^ 1][1], Vbuf[cur ^ 1][1], kv0 + 192);
    }

    if (kv0 <= q0w + 31) BODY(Kbuf[cur][0], Vbuf[cur][0], kv0);
    if (kv0 + 64 <= q0w + 31) BODY(Kbuf[cur][1], Vbuf[cur][1], kv0 + 64);

    WAIT_VM(0);  // next tile's 8 loads landed (issued one full iter ago)
    BARRIER();   // all waves done reading cur
    cur ^= 1;
  }

  // epilogue: total row-sum = own half + partner half; normalize; store O^T
  {
    const float l = lacc + __shfl_xor(lacc, 32);
    const float inv = 1.0f / l;
    const size_t row = (size_t)b * S_LEN + q0w + q31;
#pragma unroll
    for (int db = 0; db < 2; db++)
#pragma unroll
      for (int g = 0; g < 4; g++) {
        const int d0 = (db << 5) + (g << 3) + (hi << 2);
        ushort4 o;
        o.x = f2bf(oacc[db][g * 4 + 0] * inv);
        o.y = f2bf(oacc[db][g * 4 + 1] * inv);
        o.z = f2bf(oacc[db][g * 4 + 2] * inv);
        o.w = f2bf(oacc[db][g * 4 + 3] * inv);
        *(ushort4*)(&O[row * EDIM + h * HD + d0]) = o;
      }
  }
}

// ---------------------------------------------------------------------------
extern "C" void kernel_launch(void* const* d_in, const int* in_sizes, int n_in,
                              void* d_out, int out_size, void* d_ws, size_t ws_size,
                              hipStream_t stream) {
  const float* x  = (const float*)d_in[0];
  const float* Wq = (const float*)d_in[1];
  const float* Wk = (const float*)d_in[2];
  const float* Wv = (const float*)d_in[3];
  const float* Wp = (const float*)d_in[4];
  const float* bp = (const float*)d_in[5];
  float* out = (float*)d_out;

  char* ws = (char*)d_ws;
  u16* wqkvT  = (u16*)(ws);              //  6,291,456 B  [3072][1024] bf16
  u16* wprojT = (u16*)(ws + 6291456);    //  2,097,152 B  [1024][1024] bf16
  u16* Qb     = (u16*)(ws + 8388608);    // 16,777,216 B  [B,H,S,D] bf16
  u16* Kb     = (u16*)(ws + 25165824);   // 16,777,216 B  [B,H,S,D] bf16
  u16* Vtb    = (u16*)(ws + 41943040);   // 16,777,216 B  [B,H,D,S] bf16
  u16* xb     = (u16*)(ws + 58720256);   // 16,777,216 B  [B*S][E] bf16
  u16* Ob     = xb;                      // aliases xb (dead after QKV GEMM)

  pack_inputs<<<dim3(9216), dim3(256), 0, stream>>>(x, Wq, Wk, Wv, Wp,
                                                    xb, wqkvT, wprojT);
  gemm128<0><<<dim3(24, 64), dim3(256), 0, stream>>>(
      xb, wqkvT, (const float*)nullptr, Qb, Kb, Vtb, (float*)nullptr, 1024, 3072);
  attn_fused<<<dim3(1024), dim3(256), 0, stream>>>(Qb, Kb, Vtb, Ob);
  gemm128<1><<<dim3(8, 64), dim3(256), 0, stream>>>(
      Ob, wprojT, bp, (u16*)nullptr, (u16*)nullptr, (u16*)nullptr, out, 1024, 1024);
}